// Round 15
// baseline (7658.363 us; speedup 1.0000x reference)
//
#include <hip/hip_runtime.h>

#define N_NODES 1024
#define T_STEPS 12
#define JW2     4224          // padded column count = 33*128 = 22*192 (real 4160)
#define NELEM   (N_NODES*JW2) // 4,325,376
#define NELEM4  (NELEM/4)     // float4 stride between split-K partials

__device__ __forceinline__ float4 f4fma(float4 acc, float4 a, float s) {
    acc.x = fmaf(a.x, s, acc.x); acc.y = fmaf(a.y, s, acc.y);
    acc.z = fmaf(a.z, s, acc.z); acc.w = fmaf(a.w, s, acc.w);
    return acc;
}
__device__ __forceinline__ float4 f4add(float4 a, float4 b) {
    a.x += b.x; a.y += b.y; a.z += b.z; a.w += b.w; return a;
}
__device__ __forceinline__ float4 sig4(float4 v, float b) {
    float4 r;
    r.x = 1.f/(1.f+expf(-(v.x+b))); r.y = 1.f/(1.f+expf(-(v.y+b)));
    r.z = 1.f/(1.f+expf(-(v.z+b))); r.w = 1.f/(1.f+expf(-(v.w+b)));
    return r;
}
__device__ __forceinline__ float4 tanh4(float4 v, float b) {
    float4 r;
    r.x = tanhf(v.x+b); r.y = tanhf(v.y+b);
    r.z = tanhf(v.z+b); r.w = tanhf(v.w+b);
    return r;
}

// ---------------- A = softmax(relu(E E^T), axis=1) ----------------
__global__ __launch_bounds__(256) void k_supports(const float* __restrict__ E,
                                                  float* __restrict__ A) {
    int n = blockIdx.x;
    int tid = threadIdx.x;
    __shared__ float en[16];
    __shared__ float red[256];
    if (tid < 16) en[tid] = E[n*16 + tid];
    __syncthreads();
    float s[4];
    float mx = -1e30f;
#pragma unroll
    for (int i = 0; i < 4; i++) {
        int m = tid + i*256;
        float acc = 0.f;
#pragma unroll
        for (int d = 0; d < 16; d++) acc += en[d]*E[m*16 + d];
        acc = fmaxf(acc, 0.f);
        s[i] = acc;
        mx = fmaxf(mx, acc);
    }
    red[tid] = mx; __syncthreads();
    for (int st = 128; st > 0; st >>= 1) {
        if (tid < st) red[tid] = fmaxf(red[tid], red[tid+st]);
        __syncthreads();
    }
    mx = red[0]; __syncthreads();
    float sum = 0.f;
#pragma unroll
    for (int i = 0; i < 4; i++) { s[i] = expf(s[i]-mx); sum += s[i]; }
    red[tid] = sum; __syncthreads();
    for (int st = 128; st > 0; st >>= 1) {
        if (tid < st) red[tid] += red[tid+st];
        __syncthreads();
    }
    float inv = 1.f / red[0];
#pragma unroll
    for (int i = 0; i < 4; i++) A[(size_t)n*1024 + tid + i*256] = s[i]*inv;
}

// ---------------- Wout[n, idx4] = sum_d E[n,d] * Win[d, idx4] (float4) ----------------
__global__ __launch_bounds__(256) void k_mix4(const float* __restrict__ E,
                                              const float* __restrict__ Win,
                                              float* __restrict__ Wout, int SZ4) {
    int idx = blockIdx.x*256 + threadIdx.x;
    if (idx >= SZ4) return;
    const float4* w4 = (const float4*)Win;
    float4* o4 = (float4*)Wout;
    float4 w[16];
#pragma unroll
    for (int d = 0; d < 16; d++) w[d] = w4[(size_t)d*SZ4 + idx];
    int n0 = blockIdx.y * 32;
    for (int n = n0; n < n0+32; n++) {
        float4 acc = make_float4(0.f,0.f,0.f,0.f);
#pragma unroll
        for (int d = 0; d < 16; d++) {
            float e = E[n*16 + d];
            acc.x += e*w[d].x; acc.y += e*w[d].y;
            acc.z += e*w[d].z; acc.w += e*w[d].w;
        }
        o4[(size_t)n*SZ4 + idx] = acc;
    }
}

// ---------------- XS init (c-major layout, float4): XS[n][c*64+b], pads zeroed ----------------
__global__ __launch_bounds__(256) void k_init_xs4(const float* __restrict__ src,
                                                  float* __restrict__ XS) {
    int i = blockIdx.x*256 + threadIdx.x;   // f4 index; grid covers NELEM/4 exactly
    int col4 = i % (JW2/4);
    int n    = i / (JW2/4);
    float4 v = make_float4(0.f,0.f,0.f,0.f);
    if (col4 < 16) {                        // cols 0..63 = c==0 row, b = col
        int b = col4*4;
        v.x = src[((size_t)(b+0)*T_STEPS)*N_NODES + n];
        v.y = src[((size_t)(b+1)*T_STEPS)*N_NODES + n];
        v.z = src[((size_t)(b+2)*T_STEPS)*N_NODES + n];
        v.w = src[((size_t)(b+3)*T_STEPS)*N_NODES + n];
    }
    ((float4*)XS)[i] = v;
}

// ---------------- graph conv: C[n][col] = sum_m A[n][m] X[m][col] ----------------
// R12-proven: 128x192 tile, 256 threads, per-thread 8x12, BK=16, 2 barriers.
// 2.4 FLOP/LDS-byte; A-transpose staging 2-way free; X thirds 2-way free.
// split-K via blockIdx.z (z-partial -> C + z*NELEM); k-ascending order.
// At t=0 callers launch grid (1,8,nz): only cols 0..191 needed (h == 0).
__global__ __launch_bounds__(256, 2) void k_gemm(const float* __restrict__ A,
                                                 const float* __restrict__ X,
                                                 float* __restrict__ C, int KL) {
    __shared__ float As[16][132];   // [kk][row] transposed A tile (8.4 KB)
    __shared__ float Xs[16][196];   // [kk][col] (12.5 KB)
    int tid = threadIdx.x;
    int tx = tid & 15, ty = tid >> 4;
    int tx4 = tx*4, ty4 = ty*4;
    int n0 = blockIdx.y * 128;
    int j0 = blockIdx.x * 192;
    int koff = blockIdx.z * KL;
    float* Cout = C + (size_t)blockIdx.z * NELEM;
    int arow = tid >> 1, ach = (tid & 1) * 8;
    int xkk = tid >> 4;             // X-stage row 0..15

    float4 acc[2][3][4];            // [row-quad][col-third][row-in-quad] = 96 floats
#pragma unroll
    for (int q = 0; q < 2; q++)
#pragma unroll
        for (int h = 0; h < 3; h++)
#pragma unroll
            for (int r = 0; r < 4; r++) acc[q][h][r] = make_float4(0.f,0.f,0.f,0.f);

    for (int kc = koff; kc < koff + KL; kc += 16) {
        float4 av0 = *(const float4*)&A[(size_t)(n0+arow)*1024 + kc + ach];
        float4 av1 = *(const float4*)&A[(size_t)(n0+arow)*1024 + kc + ach + 4];
        float4 xv0 = *(const float4*)&X[(size_t)(kc+xkk)*JW2 + j0 + tx4];
        float4 xv1 = *(const float4*)&X[(size_t)(kc+xkk)*JW2 + j0 + 64 + tx4];
        float4 xv2 = *(const float4*)&X[(size_t)(kc+xkk)*JW2 + j0 + 128 + tx4];
        __syncthreads();
        As[ach+0][arow] = av0.x; As[ach+1][arow] = av0.y;
        As[ach+2][arow] = av0.z; As[ach+3][arow] = av0.w;
        As[ach+4][arow] = av1.x; As[ach+5][arow] = av1.y;
        As[ach+6][arow] = av1.z; As[ach+7][arow] = av1.w;
        *(float4*)&Xs[xkk][tx4]        = xv0;
        *(float4*)&Xs[xkk][64 + tx4]   = xv1;
        *(float4*)&Xs[xkk][128 + tx4]  = xv2;
        __syncthreads();
#pragma unroll
        for (int kk = 0; kk < 16; kk++) {
            float4 a0 = *(float4*)&As[kk][ty4];
            float4 a1 = *(float4*)&As[kk][64+ty4];
            float4 b0 = *(float4*)&Xs[kk][tx4];
            float4 b1 = *(float4*)&Xs[kk][64+tx4];
            float4 b2 = *(float4*)&Xs[kk][128+tx4];
            float aa0[4] = {a0.x,a0.y,a0.z,a0.w};
            float aa1[4] = {a1.x,a1.y,a1.z,a1.w};
#pragma unroll
            for (int r = 0; r < 4; r++) {
                acc[0][0][r] = f4fma(acc[0][0][r], b0, aa0[r]);
                acc[0][1][r] = f4fma(acc[0][1][r], b1, aa0[r]);
                acc[0][2][r] = f4fma(acc[0][2][r], b2, aa0[r]);
                acc[1][0][r] = f4fma(acc[1][0][r], b0, aa1[r]);
                acc[1][1][r] = f4fma(acc[1][1][r], b1, aa1[r]);
                acc[1][2][r] = f4fma(acc[1][2][r], b2, aa1[r]);
            }
        }
    }
#pragma unroll
    for (int q = 0; q < 2; q++)
#pragma unroll
        for (int r = 0; r < 4; r++) {
            size_t row = (size_t)(n0 + q*64 + ty4 + r);
#pragma unroll
            for (int h = 0; h < 3; h++)
                *(float4*)&Cout[row*JW2 + j0 + h*64 + tx4] = acc[q][h][r];
        }
}

// ---------------- gate: per-node GEMM (64b x 130kc)@(130 x 128) + sigmoid ----------------
// Staging sums nz split-K partials. cfull = # valid zg cols (65 normal, 1 at t=0:
// h==0 so A@XS cols c>=1 are exactly +0.0 -- substitute without reading).
__global__ __launch_bounds__(256) void k_gate(const float* __restrict__ XS,
                                              const float* __restrict__ ZG,
                                              int nz, int cfull,
                                              const float* __restrict__ WG,
                                              const float* __restrict__ BG,
                                              float* __restrict__ CAND,
                                              float* __restrict__ Rb) {
    int n = blockIdx.x, tid = threadIdx.x;
    __shared__ float Zl[130*64];    // 33.3 KB
    __shared__ float Wl[32*128];    // 16 KB
    {
        const float4* xs4 = (const float4*)(XS + (size_t)n*JW2);
        const float4* z4  = (const float4*)(ZG + (size_t)n*JW2);
        float4* zl4 = (float4*)Zl;
        int ilim = cfull * 16;
        for (int i = tid; i < 1040; i += 256) zl4[i] = xs4[i];
        for (int i = tid; i < 1040; i += 256) {
            float4 v = make_float4(0.f,0.f,0.f,0.f);
            if (i < ilim) {
                v = z4[i];
                for (int z = 1; z < nz; z++) v = f4add(v, z4[i + (size_t)z*NELEM4]);
            }
            zl4[1040 + i] = v;
        }
    }
    const float4* wg4 = (const float4*)(WG + (size_t)n*16640);
    float4 wreg0 = wg4[tid];
    float4 wreg1 = wg4[tid + 256];
    float4 wreg2 = wg4[tid + 512];
    float4 wreg3 = wg4[tid + 768];
    float wtail = 0.f;

    int jt = tid & 15, bt = tid >> 4;
    int j0 = jt*4, b0 = bt*4;
    float4 accz[4], accr[4];
#pragma unroll
    for (int i = 0; i < 4; i++) { accz[i] = make_float4(0,0,0,0); accr[i] = make_float4(0,0,0,0); }

    for (int c = 0; c < 5; c++) {
        int kc0 = c*32;
        int cnt = (c == 4) ? 2 : 32;
        __syncthreads();
        if (c < 4) {
            float4* wl4 = (float4*)Wl;
            wl4[tid]       = wreg0;
            wl4[tid + 256] = wreg1;
            wl4[tid + 512] = wreg2;
            wl4[tid + 768] = wreg3;
            if (c < 3) {
                wreg0 = wg4[(c+1)*1024 + tid];
                wreg1 = wg4[(c+1)*1024 + tid + 256];
                wreg2 = wg4[(c+1)*1024 + tid + 512];
                wreg3 = wg4[(c+1)*1024 + tid + 768];
            } else {
                wtail = WG[(size_t)n*16640 + 16384 + tid];   // kc 128,129
            }
        } else {
            Wl[tid] = wtail;
        }
        __syncthreads();
        for (int kk = 0; kk < cnt; kk++) {
            float4 a4 = *(float4*)&Zl[(kc0+kk)*64 + b0];
            float4 wz = *(float4*)&Wl[kk*128 + j0];
            float4 wr = *(float4*)&Wl[kk*128 + 64 + j0];
            float wza[4] = {wz.x,wz.y,wz.z,wz.w};
            float wra[4] = {wr.x,wr.y,wr.z,wr.w};
#pragma unroll
            for (int i = 0; i < 4; i++) {
                accz[i] = f4fma(accz[i], a4, wza[i]);
                accr[i] = f4fma(accr[i], a4, wra[i]);
            }
        }
    }
    const float* bg = BG + n*128;
#pragma unroll
    for (int i = 0; i < 4; i++) {
        int j = j0 + i;
        float4 z = sig4(accz[i], bg[j]);
        float4 r = sig4(accr[i], bg[64+j]);
        float4 h = *(const float4*)&XS[(size_t)n*JW2 + (1+j)*64 + b0];
        float4 zh; zh.x = z.x*h.x; zh.y = z.y*h.y; zh.z = z.z*h.z; zh.w = z.w*h.w;
        *(float4*)&CAND[(size_t)n*JW2 + (1+j)*64 + b0] = zh;
        *(float4*)&Rb[(size_t)n*4096 + j*64 + b0] = r;
    }
    if (tid < 16)
        ((float4*)(CAND + (size_t)n*JW2))[tid] = ((float4*)Zl)[tid];   // xt row
}

// ---------------- up: per-node GEMM (64 x 130)@(130 x 64) + tanh + h update ----------------
__global__ __launch_bounds__(256) void k_up(const float* __restrict__ CAND,
                                            const float* __restrict__ CG,
                                            int nz, int cfull,
                                            const float* __restrict__ WU,
                                            const float* __restrict__ BU,
                                            const float* __restrict__ Rb,
                                            float* __restrict__ XS,
                                            const float* __restrict__ src,
                                            int tnext, int hasNext) {
    int n = blockIdx.x, tid = threadIdx.x;
    __shared__ float Zl[130*64];    // 33.3 KB
    __shared__ float Wl[32*64];     // 8 KB
    {
        const float4* c4 = (const float4*)(CAND + (size_t)n*JW2);
        const float4* g4 = (const float4*)(CG + (size_t)n*JW2);
        float4* zl4 = (float4*)Zl;
        int ilim = cfull * 16;
        for (int i = tid; i < 1040; i += 256) zl4[i] = c4[i];
        for (int i = tid; i < 1040; i += 256) {
            float4 v = make_float4(0.f,0.f,0.f,0.f);
            if (i < ilim) {
                v = g4[i];
                for (int z = 1; z < nz; z++) v = f4add(v, g4[i + (size_t)z*NELEM4]);
            }
            zl4[1040 + i] = v;
        }
    }
    const float4* wu4 = (const float4*)(WU + (size_t)n*8320);
    float4 wreg0 = wu4[tid];
    float4 wreg1 = wu4[tid + 256];
    float wtail = 0.f;

    int jt = tid & 15, bt = tid >> 4;
    int j0 = jt*4, b0 = bt*4;
    float4 acc[4];
#pragma unroll
    for (int i = 0; i < 4; i++) acc[i] = make_float4(0,0,0,0);

    for (int c = 0; c < 5; c++) {
        int kc0 = c*32;
        int cnt = (c == 4) ? 2 : 32;
        __syncthreads();
        if (c < 4) {
            float4* wl4 = (float4*)Wl;
            wl4[tid]       = wreg0;
            wl4[tid + 256] = wreg1;
            if (c < 3) {
                wreg0 = wu4[(c+1)*512 + tid];
                wreg1 = wu4[(c+1)*512 + tid + 256];
            } else if (tid < 128) {
                wtail = WU[(size_t)n*8320 + 8192 + tid];     // kc 128,129
            }
        } else {
            if (tid < 128) Wl[tid] = wtail;
        }
        __syncthreads();
        for (int kk = 0; kk < cnt; kk++) {
            float4 a4 = *(float4*)&Zl[(kc0+kk)*64 + b0];
            float4 w4 = *(float4*)&Wl[kk*64 + j0];
            float wa[4] = {w4.x,w4.y,w4.z,w4.w};
#pragma unroll
            for (int i = 0; i < 4; i++) acc[i] = f4fma(acc[i], a4, wa[i]);
        }
    }
    const float* bu = BU + n*64;
#pragma unroll
    for (int i = 0; i < 4; i++) {
        int j = j0 + i;
        float4 hc = tanh4(acc[i], bu[j]);
        float4 r  = *(const float4*)&Rb[(size_t)n*4096 + j*64 + b0];
        size_t xi = (size_t)n*JW2 + (1+j)*64 + b0;
        float4 hold = *(const float4*)&XS[xi];
        float4 hn;
        hn.x = r.x*hold.x + (1.f-r.x)*hc.x;
        hn.y = r.y*hold.y + (1.f-r.y)*hc.y;
        hn.z = r.z*hold.z + (1.f-r.z)*hc.z;
        hn.w = r.w*hold.w + (1.f-r.w)*hc.w;
        *(float4*)&XS[xi] = hn;
    }
    __syncthreads();
    if (hasNext && tid < 64)
        XS[(size_t)n*JW2 + tid] = src[((size_t)tid*T_STEPS + tnext)*N_NODES + n];
}

// ---------------- head 1: OUT1 = h1.c1W + c1b ; SRC2 = src - (OUT1.c2W + c2b) ----------------
__global__ __launch_bounds__(256) void k_head1(const float* __restrict__ XS,
                                               const float* __restrict__ c1W,
                                               const float* __restrict__ c1b,
                                               const float* __restrict__ c2W,
                                               const float* __restrict__ c2b,
                                               const float* __restrict__ src,
                                               float* __restrict__ OUT1,
                                               float* __restrict__ SRC2) {
    int n = blockIdx.x, tid = threadIdx.x;
    __shared__ float Hl[64][65];
    __shared__ float w1[12][64];
    __shared__ float o1[64][13];
    for (int i = tid; i < 4096; i += 256) {
        int j = i >> 6, b = i & 63;
        Hl[b][j] = XS[(size_t)n*JW2 + 64 + i];
    }
    for (int i = tid; i < 768; i += 256) w1[i >> 6][i & 63] = c1W[i];
    __syncthreads();
    int b = tid & 63, cg = tid >> 6;
#pragma unroll
    for (int cc = 0; cc < 3; cc++) {
        int c = cg*3 + cc;
        float accv = c1b[c];
        for (int j = 0; j < 64; j++) accv += Hl[b][j]*w1[c][j];
        o1[b][c] = accv;
    }
    __syncthreads();
#pragma unroll
    for (int cc = 0; cc < 3; cc++) {
        int c = cg*3 + cc;
        float s1 = c2b[c];
#pragma unroll
        for (int j = 0; j < 12; j++) s1 += o1[b][j]*c2W[c*12 + j];
        size_t idx = ((size_t)b*12 + c)*1024 + n;
        OUT1[idx] = o1[b][c];
        SRC2[idx] = src[idx] - s1;
    }
}

// ---------------- head 2: out = OUT1 + h2.c3W + c3b ----------------
__global__ __launch_bounds__(256) void k_head2(const float* __restrict__ XS,
                                               const float* __restrict__ c3W,
                                               const float* __restrict__ c3b,
                                               const float* __restrict__ OUT1,
                                               float* __restrict__ out) {
    int n = blockIdx.x, tid = threadIdx.x;
    __shared__ float Hl[64][65];
    __shared__ float w3[12][64];
    for (int i = tid; i < 4096; i += 256) {
        int j = i >> 6, b = i & 63;
        Hl[b][j] = XS[(size_t)n*JW2 + 64 + i];
    }
    for (int i = tid; i < 768; i += 256) w3[i >> 6][i & 63] = c3W[i];
    __syncthreads();
    int b = tid & 63, cg = tid >> 6;
#pragma unroll
    for (int cc = 0; cc < 3; cc++) {
        int c = cg*3 + cc;
        float accv = c3b[c];
        for (int j = 0; j < 64; j++) accv += Hl[b][j]*w3[c][j];
        size_t idx = ((size_t)b*12 + c)*1024 + n;
        out[idx] = OUT1[idx] + accv;
    }
}

extern "C" void kernel_launch(void* const* d_in, const int* in_sizes, int n_in,
                              void* d_out, int out_size, void* d_ws, size_t ws_size,
                              hipStream_t stream) {
    const float* src  = (const float*)d_in[0];
    const float* E    = (const float*)d_in[1];
    const float* e1gW = (const float*)d_in[2];
    const float* e1gb = (const float*)d_in[3];
    const float* e1uW = (const float*)d_in[4];
    const float* e1ub = (const float*)d_in[5];
    const float* e2gW = (const float*)d_in[6];
    const float* e2gb = (const float*)d_in[7];
    const float* e2uW = (const float*)d_in[8];
    const float* e2ub = (const float*)d_in[9];
    const float* c1W  = (const float*)d_in[10];
    const float* c1b  = (const float*)d_in[11];
    const float* c2W  = (const float*)d_in[12];
    const float* c2b  = (const float*)d_in[13];
    const float* c3W  = (const float*)d_in[14];
    const float* c3b  = (const float*)d_in[15];

    // Workspace base (floats, excluding ZG): A + WG + WU + BG + BU + XS + CAND + Rb + OUT1 + SRC2
    const size_t base_noZG = 41222144;
    int nz = 1;
    if (ws_size >= (base_noZG + 4*(size_t)NELEM)*4) nz = 4;        // 234.1 MB
    else if (ws_size >= (base_noZG + 2*(size_t)NELEM)*4) nz = 2;   // 199.5 MB (proven)
    int KL = 1024 / nz;
    dim3 gfull(22, 8, nz);   // 192-col x 128-row tiles
    dim3 gt0  (1, 8, nz);    // t=0: only cols 0..191 carry nonzero input (h == 0)

    float* ws = (float*)d_ws;
    float* A    = ws;                        // 1,048,576
    float* WG   = A    + 1048576;            // 17,039,360
    float* WU   = WG   + 17039360;           //  8,519,680
    float* BG   = WU   + 8519680;            //    131,072
    float* BU   = BG   + 131072;             //     65,536
    float* XS   = BU   + 65536;              //  NELEM
    float* ZG   = XS   + NELEM;              //  nz * NELEM (contiguous partials)
    float* CAND = ZG   + (size_t)nz*NELEM;
    float* Rb   = CAND + NELEM;              //  4,194,304
    float* OUT1 = Rb   + 4194304;            //    786,432
    float* SRC2 = OUT1 + 786432;             //    786,432

    k_supports<<<N_NODES, 256, 0, stream>>>(E, A);

    auto run_encoder = [&](const float* s, const float* gW, const float* gb,
                           const float* uW, const float* ub) {
        k_mix4<<<dim3(17, 32), 256, 0, stream>>>(E, gW, WG, 4160);   // 16640/4
        k_mix4<<<dim3(9, 32),  256, 0, stream>>>(E, uW, WU, 2080);   //  8320/4
        k_mix4<<<dim3(1, 32),  256, 0, stream>>>(E, gb, BG, 32);     //   128/4
        k_mix4<<<dim3(1, 32),  256, 0, stream>>>(E, ub, BU, 16);     //    64/4
        k_init_xs4<<<NELEM/4/256, 256, 0, stream>>>(s, XS);
        for (int t = 0; t < T_STEPS; t++) {
            int cf = (t == 0) ? 1 : 65;      // valid zg cols (t=0: h==0 -> only c=0)
            k_gemm<<<(t == 0) ? gt0 : gfull, 256, 0, stream>>>(A, XS, ZG, KL);
            k_gate<<<N_NODES, 256, 0, stream>>>(XS, ZG, nz, cf, WG, BG, CAND, Rb);
            k_gemm<<<(t == 0) ? gt0 : gfull, 256, 0, stream>>>(A, CAND, ZG, KL);
            k_up<<<N_NODES, 256, 0, stream>>>(CAND, ZG, nz, cf, WU, BU, Rb, XS, s,
                                              t + 1, (t + 1 < T_STEPS) ? 1 : 0);
        }
    };

    run_encoder(src, e1gW, e1gb, e1uW, e1ub);
    k_head1<<<N_NODES, 256, 0, stream>>>(XS, c1W, c1b, c2W, c2b, src, OUT1, SRC2);
    run_encoder(SRC2, e2gW, e2gb, e2uW, e2ub);
    k_head2<<<N_NODES, 256, 0, stream>>>(XS, c3W, c3b, OUT1, (float*)d_out);
}

// Round 16
// 7630.798 us; speedup vs baseline: 1.0036x; 1.0036x over previous
//
#include <hip/hip_runtime.h>

#define N_NODES 1024
#define T_STEPS 12
#define JW2     4224          // padded column count = 33*128 = 22*192 (real 4160)
#define NELEM   (N_NODES*JW2) // 4,325,376
#define NELEM4  (NELEM/4)     // float4 stride between split-K partials

__device__ __forceinline__ float4 f4fma(float4 acc, float4 a, float s) {
    acc.x = fmaf(a.x, s, acc.x); acc.y = fmaf(a.y, s, acc.y);
    acc.z = fmaf(a.z, s, acc.z); acc.w = fmaf(a.w, s, acc.w);
    return acc;
}
__device__ __forceinline__ float4 f4add(float4 a, float4 b) {
    a.x += b.x; a.y += b.y; a.z += b.z; a.w += b.w; return a;
}
__device__ __forceinline__ float4 sig4(float4 v, float b) {
    float4 r;
    r.x = 1.f/(1.f+expf(-(v.x+b))); r.y = 1.f/(1.f+expf(-(v.y+b)));
    r.z = 1.f/(1.f+expf(-(v.z+b))); r.w = 1.f/(1.f+expf(-(v.w+b)));
    return r;
}
__device__ __forceinline__ float4 tanh4(float4 v, float b) {
    float4 r;
    r.x = tanhf(v.x+b); r.y = tanhf(v.y+b);
    r.z = tanhf(v.z+b); r.w = tanhf(v.w+b);
    return r;
}

// ---------------- A = softmax(relu(E E^T), axis=1) ----------------
__global__ __launch_bounds__(256) void k_supports(const float* __restrict__ E,
                                                  float* __restrict__ A) {
    int n = blockIdx.x;
    int tid = threadIdx.x;
    __shared__ float en[16];
    __shared__ float red[256];
    if (tid < 16) en[tid] = E[n*16 + tid];
    __syncthreads();
    float s[4];
    float mx = -1e30f;
#pragma unroll
    for (int i = 0; i < 4; i++) {
        int m = tid + i*256;
        float acc = 0.f;
#pragma unroll
        for (int d = 0; d < 16; d++) acc += en[d]*E[m*16 + d];
        acc = fmaxf(acc, 0.f);
        s[i] = acc;
        mx = fmaxf(mx, acc);
    }
    red[tid] = mx; __syncthreads();
    for (int st = 128; st > 0; st >>= 1) {
        if (tid < st) red[tid] = fmaxf(red[tid], red[tid+st]);
        __syncthreads();
    }
    mx = red[0]; __syncthreads();
    float sum = 0.f;
#pragma unroll
    for (int i = 0; i < 4; i++) { s[i] = expf(s[i]-mx); sum += s[i]; }
    red[tid] = sum; __syncthreads();
    for (int st = 128; st > 0; st >>= 1) {
        if (tid < st) red[tid] += red[tid+st];
        __syncthreads();
    }
    float inv = 1.f / red[0];
#pragma unroll
    for (int i = 0; i < 4; i++) A[(size_t)n*1024 + tid + i*256] = s[i]*inv;
}

// ---------------- Wout[n, idx] = sum_d E[n,d] * Win[d, idx] ----------------
__global__ __launch_bounds__(256) void k_mix(const float* __restrict__ E,
                                             const float* __restrict__ Win,
                                             float* __restrict__ Wout, int SZ) {
    int idx = blockIdx.x*256 + threadIdx.x;
    if (idx >= SZ) return;
    float w[16];
#pragma unroll
    for (int d = 0; d < 16; d++) w[d] = Win[(size_t)d*SZ + idx];
    int n0 = blockIdx.y * 32;
    for (int n = n0; n < n0+32; n++) {
        float acc = 0.f;
#pragma unroll
        for (int d = 0; d < 16; d++) acc += E[n*16 + d]*w[d];
        Wout[(size_t)n*SZ + idx] = acc;
    }
}

// ---------------- XS init (c-major layout): XS[n][c*64+b], pads zeroed ----------------
__global__ __launch_bounds__(256) void k_init_xs(const float* __restrict__ src,
                                                 float* __restrict__ XS) {
    int i = blockIdx.x*256 + threadIdx.x;   // grid covers NELEM exactly
    int col = i % JW2;
    int n   = i / JW2;
    float v = 0.f;
    if (col < 64) v = src[((size_t)col*T_STEPS)*N_NODES + n];  // c==0 row: xt(b=col)
    XS[i] = v;
}

// ---------------- graph conv: C[n][col] = sum_m A[n][m] X[m][col] ----------------
// R12-proven: 128x192 tile, 256 threads, per-thread 8x12, BK=16, 2 barriers.
// 2.4 FLOP/LDS-byte; A-transpose staging 2-way free; X thirds 2-way free.
// split-K via blockIdx.z (z-partial -> C + z*NELEM); k-ascending order.
// At t=0 callers launch grid (1,8,nz): only cols 0..191 needed (h == 0).
__global__ __launch_bounds__(256, 2) void k_gemm(const float* __restrict__ A,
                                                 const float* __restrict__ X,
                                                 float* __restrict__ C, int KL) {
    __shared__ float As[16][132];   // [kk][row] transposed A tile (8.4 KB)
    __shared__ float Xs[16][196];   // [kk][col] (12.5 KB)
    int tid = threadIdx.x;
    int tx = tid & 15, ty = tid >> 4;
    int tx4 = tx*4, ty4 = ty*4;
    int n0 = blockIdx.y * 128;
    int j0 = blockIdx.x * 192;
    int koff = blockIdx.z * KL;
    float* Cout = C + (size_t)blockIdx.z * NELEM;
    int arow = tid >> 1, ach = (tid & 1) * 8;
    int xkk = tid >> 4;             // X-stage row 0..15

    float4 acc[2][3][4];            // [row-quad][col-third][row-in-quad] = 96 floats
#pragma unroll
    for (int q = 0; q < 2; q++)
#pragma unroll
        for (int h = 0; h < 3; h++)
#pragma unroll
            for (int r = 0; r < 4; r++) acc[q][h][r] = make_float4(0.f,0.f,0.f,0.f);

    for (int kc = koff; kc < koff + KL; kc += 16) {
        float4 av0 = *(const float4*)&A[(size_t)(n0+arow)*1024 + kc + ach];
        float4 av1 = *(const float4*)&A[(size_t)(n0+arow)*1024 + kc + ach + 4];
        float4 xv0 = *(const float4*)&X[(size_t)(kc+xkk)*JW2 + j0 + tx4];
        float4 xv1 = *(const float4*)&X[(size_t)(kc+xkk)*JW2 + j0 + 64 + tx4];
        float4 xv2 = *(const float4*)&X[(size_t)(kc+xkk)*JW2 + j0 + 128 + tx4];
        __syncthreads();
        As[ach+0][arow] = av0.x; As[ach+1][arow] = av0.y;
        As[ach+2][arow] = av0.z; As[ach+3][arow] = av0.w;
        As[ach+4][arow] = av1.x; As[ach+5][arow] = av1.y;
        As[ach+6][arow] = av1.z; As[ach+7][arow] = av1.w;
        *(float4*)&Xs[xkk][tx4]        = xv0;
        *(float4*)&Xs[xkk][64 + tx4]   = xv1;
        *(float4*)&Xs[xkk][128 + tx4]  = xv2;
        __syncthreads();
#pragma unroll
        for (int kk = 0; kk < 16; kk++) {
            float4 a0 = *(float4*)&As[kk][ty4];
            float4 a1 = *(float4*)&As[kk][64+ty4];
            float4 b0 = *(float4*)&Xs[kk][tx4];
            float4 b1 = *(float4*)&Xs[kk][64+tx4];
            float4 b2 = *(float4*)&Xs[kk][128+tx4];
            float aa0[4] = {a0.x,a0.y,a0.z,a0.w};
            float aa1[4] = {a1.x,a1.y,a1.z,a1.w};
#pragma unroll
            for (int r = 0; r < 4; r++) {
                acc[0][0][r] = f4fma(acc[0][0][r], b0, aa0[r]);
                acc[0][1][r] = f4fma(acc[0][1][r], b1, aa0[r]);
                acc[0][2][r] = f4fma(acc[0][2][r], b2, aa0[r]);
                acc[1][0][r] = f4fma(acc[1][0][r], b0, aa1[r]);
                acc[1][1][r] = f4fma(acc[1][1][r], b1, aa1[r]);
                acc[1][2][r] = f4fma(acc[1][2][r], b2, aa1[r]);
            }
        }
    }
#pragma unroll
    for (int q = 0; q < 2; q++)
#pragma unroll
        for (int r = 0; r < 4; r++) {
            size_t row = (size_t)(n0 + q*64 + ty4 + r);
#pragma unroll
            for (int h = 0; h < 3; h++)
                *(float4*)&Cout[row*JW2 + j0 + h*64 + tx4] = acc[q][h][r];
        }
}

// ---------------- gate: per-node GEMM (64b x 130kc)@(130 x 128) + sigmoid ----------------
// Staging sums nz split-K partials. cfull = # valid zg cols (65 normal, 1 at t=0:
// h==0 so A@XS cols c>=1 are exactly +0.0 -- substitute without reading).
__global__ __launch_bounds__(256) void k_gate(const float* __restrict__ XS,
                                              const float* __restrict__ ZG,
                                              int nz, int cfull,
                                              const float* __restrict__ WG,
                                              const float* __restrict__ BG,
                                              float* __restrict__ CAND,
                                              float* __restrict__ Rb) {
    int n = blockIdx.x, tid = threadIdx.x;
    __shared__ float Zl[130*64];    // 33.3 KB
    __shared__ float Wl[32*128];    // 16 KB
    {
        const float4* xs4 = (const float4*)(XS + (size_t)n*JW2);
        const float4* z4  = (const float4*)(ZG + (size_t)n*JW2);
        float4* zl4 = (float4*)Zl;
        int ilim = cfull * 16;
        for (int i = tid; i < 1040; i += 256) zl4[i] = xs4[i];
        for (int i = tid; i < 1040; i += 256) {
            float4 v = make_float4(0.f,0.f,0.f,0.f);
            if (i < ilim) {
                v = z4[i];
                for (int z = 1; z < nz; z++) v = f4add(v, z4[i + (size_t)z*NELEM4]);
            }
            zl4[1040 + i] = v;
        }
    }
    const float4* wg4 = (const float4*)(WG + (size_t)n*16640);
    float4 wreg0 = wg4[tid];
    float4 wreg1 = wg4[tid + 256];
    float4 wreg2 = wg4[tid + 512];
    float4 wreg3 = wg4[tid + 768];
    float wtail = 0.f;

    int jt = tid & 15, bt = tid >> 4;
    int j0 = jt*4, b0 = bt*4;
    float4 accz[4], accr[4];
#pragma unroll
    for (int i = 0; i < 4; i++) { accz[i] = make_float4(0,0,0,0); accr[i] = make_float4(0,0,0,0); }

    for (int c = 0; c < 5; c++) {
        int kc0 = c*32;
        int cnt = (c == 4) ? 2 : 32;
        __syncthreads();
        if (c < 4) {
            float4* wl4 = (float4*)Wl;
            wl4[tid]       = wreg0;
            wl4[tid + 256] = wreg1;
            wl4[tid + 512] = wreg2;
            wl4[tid + 768] = wreg3;
            if (c < 3) {
                wreg0 = wg4[(c+1)*1024 + tid];
                wreg1 = wg4[(c+1)*1024 + tid + 256];
                wreg2 = wg4[(c+1)*1024 + tid + 512];
                wreg3 = wg4[(c+1)*1024 + tid + 768];
            } else {
                wtail = WG[(size_t)n*16640 + 16384 + tid];   // kc 128,129
            }
        } else {
            Wl[tid] = wtail;
        }
        __syncthreads();
        for (int kk = 0; kk < cnt; kk++) {
            float4 a4 = *(float4*)&Zl[(kc0+kk)*64 + b0];
            float4 wz = *(float4*)&Wl[kk*128 + j0];
            float4 wr = *(float4*)&Wl[kk*128 + 64 + j0];
            float wza[4] = {wz.x,wz.y,wz.z,wz.w};
            float wra[4] = {wr.x,wr.y,wr.z,wr.w};
#pragma unroll
            for (int i = 0; i < 4; i++) {
                accz[i] = f4fma(accz[i], a4, wza[i]);
                accr[i] = f4fma(accr[i], a4, wra[i]);
            }
        }
    }
    const float* bg = BG + n*128;
#pragma unroll
    for (int i = 0; i < 4; i++) {
        int j = j0 + i;
        float4 z = sig4(accz[i], bg[j]);
        float4 r = sig4(accr[i], bg[64+j]);
        float4 h = *(const float4*)&XS[(size_t)n*JW2 + (1+j)*64 + b0];
        float4 zh; zh.x = z.x*h.x; zh.y = z.y*h.y; zh.z = z.z*h.z; zh.w = z.w*h.w;
        *(float4*)&CAND[(size_t)n*JW2 + (1+j)*64 + b0] = zh;
        *(float4*)&Rb[(size_t)n*4096 + j*64 + b0] = r;
    }
    if (tid < 16)
        ((float4*)(CAND + (size_t)n*JW2))[tid] = ((float4*)Zl)[tid];   // xt row
}

// ---------------- up: per-node GEMM (64 x 130)@(130 x 64) + tanh + h update ----------------
__global__ __launch_bounds__(256) void k_up(const float* __restrict__ CAND,
                                            const float* __restrict__ CG,
                                            int nz, int cfull,
                                            const float* __restrict__ WU,
                                            const float* __restrict__ BU,
                                            const float* __restrict__ Rb,
                                            float* __restrict__ XS,
                                            const float* __restrict__ src,
                                            int tnext, int hasNext) {
    int n = blockIdx.x, tid = threadIdx.x;
    __shared__ float Zl[130*64];    // 33.3 KB
    __shared__ float Wl[32*64];     // 8 KB
    {
        const float4* c4 = (const float4*)(CAND + (size_t)n*JW2);
        const float4* g4 = (const float4*)(CG + (size_t)n*JW2);
        float4* zl4 = (float4*)Zl;
        int ilim = cfull * 16;
        for (int i = tid; i < 1040; i += 256) zl4[i] = c4[i];
        for (int i = tid; i < 1040; i += 256) {
            float4 v = make_float4(0.f,0.f,0.f,0.f);
            if (i < ilim) {
                v = g4[i];
                for (int z = 1; z < nz; z++) v = f4add(v, g4[i + (size_t)z*NELEM4]);
            }
            zl4[1040 + i] = v;
        }
    }
    const float4* wu4 = (const float4*)(WU + (size_t)n*8320);
    float4 wreg0 = wu4[tid];
    float4 wreg1 = wu4[tid + 256];
    float wtail = 0.f;

    int jt = tid & 15, bt = tid >> 4;
    int j0 = jt*4, b0 = bt*4;
    float4 acc[4];
#pragma unroll
    for (int i = 0; i < 4; i++) acc[i] = make_float4(0,0,0,0);

    for (int c = 0; c < 5; c++) {
        int kc0 = c*32;
        int cnt = (c == 4) ? 2 : 32;
        __syncthreads();
        if (c < 4) {
            float4* wl4 = (float4*)Wl;
            wl4[tid]       = wreg0;
            wl4[tid + 256] = wreg1;
            if (c < 3) {
                wreg0 = wu4[(c+1)*512 + tid];
                wreg1 = wu4[(c+1)*512 + tid + 256];
            } else if (tid < 128) {
                wtail = WU[(size_t)n*8320 + 8192 + tid];     // kc 128,129
            }
        } else {
            if (tid < 128) Wl[tid] = wtail;
        }
        __syncthreads();
        for (int kk = 0; kk < cnt; kk++) {
            float4 a4 = *(float4*)&Zl[(kc0+kk)*64 + b0];
            float4 w4 = *(float4*)&Wl[kk*64 + j0];
            float wa[4] = {w4.x,w4.y,w4.z,w4.w};
#pragma unroll
            for (int i = 0; i < 4; i++) acc[i] = f4fma(acc[i], a4, wa[i]);
        }
    }
    const float* bu = BU + n*64;
#pragma unroll
    for (int i = 0; i < 4; i++) {
        int j = j0 + i;
        float4 hc = tanh4(acc[i], bu[j]);
        float4 r  = *(const float4*)&Rb[(size_t)n*4096 + j*64 + b0];
        size_t xi = (size_t)n*JW2 + (1+j)*64 + b0;
        float4 hold = *(const float4*)&XS[xi];
        float4 hn;
        hn.x = r.x*hold.x + (1.f-r.x)*hc.x;
        hn.y = r.y*hold.y + (1.f-r.y)*hc.y;
        hn.z = r.z*hold.z + (1.f-r.z)*hc.z;
        hn.w = r.w*hold.w + (1.f-r.w)*hc.w;
        *(float4*)&XS[xi] = hn;
    }
    __syncthreads();
    if (hasNext && tid < 64)
        XS[(size_t)n*JW2 + tid] = src[((size_t)tid*T_STEPS + tnext)*N_NODES + n];
}

// ---------------- head 1: OUT1 = h1.c1W + c1b ; SRC2 = src - (OUT1.c2W + c2b) ----------------
__global__ __launch_bounds__(256) void k_head1(const float* __restrict__ XS,
                                               const float* __restrict__ c1W,
                                               const float* __restrict__ c1b,
                                               const float* __restrict__ c2W,
                                               const float* __restrict__ c2b,
                                               const float* __restrict__ src,
                                               float* __restrict__ OUT1,
                                               float* __restrict__ SRC2) {
    int n = blockIdx.x, tid = threadIdx.x;
    __shared__ float Hl[64][65];
    __shared__ float w1[12][64];
    __shared__ float o1[64][13];
    for (int i = tid; i < 4096; i += 256) {
        int j = i >> 6, b = i & 63;
        Hl[b][j] = XS[(size_t)n*JW2 + 64 + i];
    }
    for (int i = tid; i < 768; i += 256) w1[i >> 6][i & 63] = c1W[i];
    __syncthreads();
    int b = tid & 63, cg = tid >> 6;
#pragma unroll
    for (int cc = 0; cc < 3; cc++) {
        int c = cg*3 + cc;
        float accv = c1b[c];
        for (int j = 0; j < 64; j++) accv += Hl[b][j]*w1[c][j];
        o1[b][c] = accv;
    }
    __syncthreads();
#pragma unroll
    for (int cc = 0; cc < 3; cc++) {
        int c = cg*3 + cc;
        float s1 = c2b[c];
#pragma unroll
        for (int j = 0; j < 12; j++) s1 += o1[b][j]*c2W[c*12 + j];
        size_t idx = ((size_t)b*12 + c)*1024 + n;
        OUT1[idx] = o1[b][c];
        SRC2[idx] = src[idx] - s1;
    }
}

// ---------------- head 2: out = OUT1 + h2.c3W + c3b ----------------
__global__ __launch_bounds__(256) void k_head2(const float* __restrict__ XS,
                                               const float* __restrict__ c3W,
                                               const float* __restrict__ c3b,
                                               const float* __restrict__ OUT1,
                                               float* __restrict__ out) {
    int n = blockIdx.x, tid = threadIdx.x;
    __shared__ float Hl[64][65];
    __shared__ float w3[12][64];
    for (int i = tid; i < 4096; i += 256) {
        int j = i >> 6, b = i & 63;
        Hl[b][j] = XS[(size_t)n*JW2 + 64 + i];
    }
    for (int i = tid; i < 768; i += 256) w3[i >> 6][i & 63] = c3W[i];
    __syncthreads();
    int b = tid & 63, cg = tid >> 6;
#pragma unroll
    for (int cc = 0; cc < 3; cc++) {
        int c = cg*3 + cc;
        float accv = c3b[c];
        for (int j = 0; j < 64; j++) accv += Hl[b][j]*w3[c][j];
        size_t idx = ((size_t)b*12 + c)*1024 + n;
        out[idx] = OUT1[idx] + accv;
    }
}

extern "C" void kernel_launch(void* const* d_in, const int* in_sizes, int n_in,
                              void* d_out, int out_size, void* d_ws, size_t ws_size,
                              hipStream_t stream) {
    const float* src  = (const float*)d_in[0];
    const float* E    = (const float*)d_in[1];
    const float* e1gW = (const float*)d_in[2];
    const float* e1gb = (const float*)d_in[3];
    const float* e1uW = (const float*)d_in[4];
    const float* e1ub = (const float*)d_in[5];
    const float* e2gW = (const float*)d_in[6];
    const float* e2gb = (const float*)d_in[7];
    const float* e2uW = (const float*)d_in[8];
    const float* e2ub = (const float*)d_in[9];
    const float* c1W  = (const float*)d_in[10];
    const float* c1b  = (const float*)d_in[11];
    const float* c2W  = (const float*)d_in[12];
    const float* c2b  = (const float*)d_in[13];
    const float* c3W  = (const float*)d_in[14];
    const float* c3b  = (const float*)d_in[15];

    // Workspace base (floats, excluding ZG): A + WG + WU + BG + BU + XS + CAND + Rb + OUT1 + SRC2
    const size_t base_noZG = 41222144;
    int nz = 1;
    if (ws_size >= (base_noZG + 4*(size_t)NELEM)*4) nz = 4;        // 234.1 MB
    else if (ws_size >= (base_noZG + 2*(size_t)NELEM)*4) nz = 2;   // 199.5 MB (proven)
    int KL = 1024 / nz;
    dim3 gfull(22, 8, nz);   // 192-col x 128-row tiles
    dim3 gt0  (1, 8, nz);    // t=0: only cols 0..191 carry nonzero input (h == 0)

    float* ws = (float*)d_ws;
    float* A    = ws;                        // 1,048,576
    float* WG   = A    + 1048576;            // 17,039,360
    float* WU   = WG   + 17039360;           //  8,519,680
    float* BG   = WU   + 8519680;            //    131,072
    float* BU   = BG   + 131072;             //     65,536
    float* XS   = BU   + 65536;              //  NELEM
    float* ZG   = XS   + NELEM;              //  nz * NELEM (contiguous partials)
    float* CAND = ZG   + (size_t)nz*NELEM;
    float* Rb   = CAND + NELEM;              //  4,194,304
    float* OUT1 = Rb   + 4194304;            //    786,432
    float* SRC2 = OUT1 + 786432;             //    786,432

    k_supports<<<N_NODES, 256, 0, stream>>>(E, A);

    auto run_encoder = [&](const float* s, const float* gW, const float* gb,
                           const float* uW, const float* ub) {
        k_mix<<<dim3(65, 32), 256, 0, stream>>>(E, gW, WG, 16640);
        k_mix<<<dim3(33, 32), 256, 0, stream>>>(E, uW, WU, 8320);
        k_mix<<<dim3(1, 32),  256, 0, stream>>>(E, gb, BG, 128);
        k_mix<<<dim3(1, 32),  256, 0, stream>>>(E, ub, BU, 64);
        k_init_xs<<<NELEM/256, 256, 0, stream>>>(s, XS);
        for (int t = 0; t < T_STEPS; t++) {
            int cf = (t == 0) ? 1 : 65;      // valid zg cols (t=0: h==0 -> only c=0)
            k_gemm<<<(t == 0) ? gt0 : gfull, 256, 0, stream>>>(A, XS, ZG, KL);
            k_gate<<<N_NODES, 256, 0, stream>>>(XS, ZG, nz, cf, WG, BG, CAND, Rb);
            k_gemm<<<(t == 0) ? gt0 : gfull, 256, 0, stream>>>(A, CAND, ZG, KL);
            k_up<<<N_NODES, 256, 0, stream>>>(CAND, ZG, nz, cf, WU, BU, Rb, XS, s,
                                              t + 1, (t + 1 < T_STEPS) ? 1 : 0);
        }
    };

    run_encoder(src, e1gW, e1gb, e1uW, e1ub);
    k_head1<<<N_NODES, 256, 0, stream>>>(XS, c1W, c1b, c2W, c2b, src, OUT1, SRC2);
    run_encoder(SRC2, e2gW, e2gb, e2uW, e2ub);
    k_head2<<<N_NODES, 256, 0, stream>>>(XS, c3W, c3b, OUT1, (float*)d_out);
}